// Round 5
// baseline (1145.821 us; speedup 1.0000x reference)
//
#include <hip/hip_runtime.h>
#include <cstdint>
#include <cstddef>

// CTC-CRF logZ forward: S=1024 states, NZ=5.
// Linear-domain recursion with lagged power-of-2 renormalization:
//   A[t][s] = 2^(K*alpha[t][s] - C_t),  K = log2(e)
//   A'[s]   = sum_j 2^(K*m_j - e_t) * A[pred_j],   C_{t+1} = C_t + e_t
// e_t = biased exponent of broadcast A[t][0] (uniform-address LDS read).
// 512 threads/block, 2 states/thread (states 2u, 2u+1): both share pred base
// p = u>>1, so 4 stride-1 conflict-free ds_read_b32 (lane pairs broadcast)
// serve both states, and the alpha write is one contiguous ds_write_b64 into
// a LINEAR double-buffered layout -> zero LDS bank conflicts (vs the 8-way
// conflicted permuted write of the previous round).
// Scores global->VGPR (b128+b128+b64 per thread per step), depth-3 rotating
// 4-set register pipeline (statically indexed, running pointer per set).
// Raw s_barrier + lgkmcnt(0) only: prefetches stay in flight across barriers.

#define NB 32
#define SD 1024
#define CD 5120
#define NT 512

typedef float f4a __attribute__((ext_vector_type(4), aligned(4)));
typedef float f2a __attribute__((ext_vector_type(2), aligned(8)));

__device__ __forceinline__ float fexp2(float x) { return __builtin_amdgcn_exp2f(x); }
__device__ __forceinline__ float flog2(float x) { return __builtin_amdgcn_logf(x); }

__global__ void __launch_bounds__(NT) ctc_logz(const float* __restrict__ scores,
                                               float* __restrict__ out, int T) {
  __shared__ float ap[2 * SD];   // linear A, double-buffered
  __shared__ float red[8];

  const int u = threadIdx.x;
  const int n = blockIdx.x;
  const int lane = u & 63;
  const int wid = u >> 6;
  const int pb = u >> 1;         // shared predecessor base for states 2u,2u+1

  ap[u] = 1.f; ap[u + 512] = 1.f; ap[u + 1024] = 1.f; ap[u + 1536] = 1.f;
  float a0 = 1.f, a1 = 1.f;      // A[2u], A[2u+1]
  int cacc = 0;                  // sum of biased exponents

  const float K = 1.44269504088896340736f;    // log2(e)
  const float LN2 = 0.69314718055994530942f;  // ln(2)

  const float* sn = scores + (size_t)n * CD + (size_t)u * 10;
  const size_t tstr = (size_t)NB * CD;
  const size_t str4 = 4 * tstr;

  auto CP = [&](int t, const f4a& qa, const f4a& qb, const f2a& qc) {
    const int rb = ((t + 1) & 1) * SD;
    const float R = ap[rb];                           // uniform -> broadcast
    const int xb = (__float_as_int(R) >> 23) & 0xFF;  // biased exponent
    cacc += xb;
    const float nLf = (float)(127 - xb);
    const float p0 = ap[rb + pb];
    const float p1 = ap[rb + pb + 256];
    const float p2 = ap[rb + pb + 512];
    const float p3 = ap[rb + pb + 768];
    // state 2u: scores qa.xyzw, qb.x
    float s0 = fexp2(__builtin_fmaf(qa.x, K, nLf)) * a0;
    s0 = __builtin_fmaf(fexp2(__builtin_fmaf(qa.y, K, nLf)), p0, s0);
    s0 = __builtin_fmaf(fexp2(__builtin_fmaf(qa.z, K, nLf)), p1, s0);
    s0 = __builtin_fmaf(fexp2(__builtin_fmaf(qa.w, K, nLf)), p2, s0);
    s0 = __builtin_fmaf(fexp2(__builtin_fmaf(qb.x, K, nLf)), p3, s0);
    // state 2u+1: scores qb.yzw, qc.xy
    float s1 = fexp2(__builtin_fmaf(qb.y, K, nLf)) * a1;
    s1 = __builtin_fmaf(fexp2(__builtin_fmaf(qb.z, K, nLf)), p0, s1);
    s1 = __builtin_fmaf(fexp2(__builtin_fmaf(qb.w, K, nLf)), p1, s1);
    s1 = __builtin_fmaf(fexp2(__builtin_fmaf(qc.x, K, nLf)), p2, s1);
    s1 = __builtin_fmaf(fexp2(__builtin_fmaf(qc.y, K, nLf)), p3, s1);
    a0 = s0; a1 = s1;
    f2a w; w.x = s0; w.y = s1;
    *(f2a*)&ap[(t & 1) * SD + (u << 1)] = w;          // ds_write_b64, conflict-free
    // drain LDS before barrier; global prefetches stay in flight.
    asm volatile("s_waitcnt lgkmcnt(0)\n\ts_barrier" ::: "memory");
  };

  // 4 register sets (10 floats each) + running pointers. Clamped prologue.
#define PRO(c)                                                              \
  const float* P##c = sn + (size_t)((c) < T ? (c) : T - 1) * tstr;          \
  f4a qa##c = *(const f4a*)P##c;                                            \
  f4a qb##c = *(const f4a*)(P##c + 4);                                      \
  f2a qc##c = *(const f2a*)(P##c + 8);                                      \
  P##c += str4;
  PRO(0) PRO(1) PRO(2) PRO(3)
#undef PRO

  __syncthreads();  // ap init visible

#define RL(c)                                                               \
  qa##c = *(const f4a*)P##c;                                                \
  qb##c = *(const f4a*)(P##c + 4);                                          \
  qc##c = *(const f2a*)(P##c + 8);                                          \
  P##c += str4;

  int t = 0;
  for (; t + 8 <= T; t += 4) {
    CP(t + 0, qa0, qb0, qc0); RL(0)
    CP(t + 1, qa1, qb1, qc1); RL(1)
    CP(t + 2, qa2, qb2, qc2); RL(2)
    CP(t + 3, qa3, qb3, qc3); RL(3)
  }
#undef RL

#define EPI1(c)                                                             \
  if (t + (c) < T) {                                                        \
    CP(t + (c), qa##c, qb##c, qc##c);                                       \
    if (t + 4 + (c) < T) {                                                  \
      qa##c = *(const f4a*)P##c; qb##c = *(const f4a*)(P##c + 4);           \
      qc##c = *(const f2a*)(P##c + 8);                                      \
    }                                                                       \
  }
  EPI1(0) EPI1(1) EPI1(2) EPI1(3)
#undef EPI1
  t += 4;
#define EPI2(c) if (t + (c) < T) CP(t + (c), qa##c, qb##c, qc##c);
  EPI2(0) EPI2(1) EPI2(2) EPI2(3)
#undef EPI2

  // logZ[n] = ln2 * (cacc - 127*T + log2(sum_s A_T[s]))
  float v = a0 + a1;
#pragma unroll
  for (int d = 1; d < 64; d <<= 1) v += __shfl_xor(v, d, 64);
  if (lane == 0) red[wid] = v;
  __syncthreads();
  if (u == 0) {
    float ssum = red[0];
#pragma unroll
    for (int i = 1; i < 8; ++i) ssum += red[i];
    out[n] = LN2 * ((float)(cacc - 127 * T) + flog2(ssum));
  }
}

extern "C" void kernel_launch(void* const* d_in, const int* in_sizes, int n_in,
                              void* d_out, int out_size, void* d_ws, size_t ws_size,
                              hipStream_t stream) {
  const float* scores = (const float*)d_in[0];
  float* out = (float*)d_out;
  const long long tot = (long long)in_sizes[0];
  const int T = (int)(tot / ((long long)NB * CD));
  ctc_logz<<<dim3(NB), dim3(NT), 0, stream>>>(scores, out, T);
}

// Round 7
// 761.303 us; speedup vs baseline: 1.5051x; 1.5051x over previous
//
#include <hip/hip_runtime.h>
#include <cstdint>
#include <cstddef>

// CTC-CRF logZ forward: S=1024, NZ=5, linear-domain with damped pow2 renorm.
//   A'[s] = e0*A[s] + e1*A[p] + e2*A[256+p] + e3*A[512+p] + e4*A[768+p]
//   e_j = 2^(K*m_j - L_t);  L_{t+1} = (expfield(A[t][0]) - 127) >> 2
// Renorm controller: measure every step (uniform LDS broadcast), apply with
// LAG 1 and GAIN 1/4 -> z^2 - z + 1/4, double root 0.5, critically damped
// (R6's 4-step full-gain lag was x3-per-window unstable -> NaN).
// 32 blocks x 1024 threads (16 waves; R5 proved 8 waves latency-bound).
// DS diet: threads 4p..4p+3 need the SAME 4 preds {p+256c}; each reads ONE
// via conflict-free XOR-swizzled ds_read_b32, quad-exchanged via DPP
// quad_perm (VALU pipe). Write: 1 swizzled b32, 2-way = free.
// Scores global->VGPR (b128+dword), depth-4 rotating register sets.
// Raw s_barrier + lgkmcnt(0): global prefetches stay in flight.

#define NB 32
#define SD 1024
#define CD 5120

typedef float f4a __attribute__((ext_vector_type(4), aligned(4)));

__device__ __forceinline__ float fexp2(float x) { return __builtin_amdgcn_exp2f(x); }
__device__ __forceinline__ float flog2(float x) { return __builtin_amdgcn_logf(x); }

template <int CTRL>
__device__ __forceinline__ float dppq(float v) {
  return __int_as_float(
      __builtin_amdgcn_update_dpp(0, __float_as_int(v), CTRL, 0xF, 0xF, true));
}

__global__ void __launch_bounds__(1024) ctc_logz(const float* __restrict__ scores,
                                                 float* __restrict__ out, int T) {
  __shared__ float ap[2 * SD];   // swizzled A, double-buffered
  __shared__ float red[16];

  const int u = threadIdx.x;
  const int n = blockIdx.x;
  const int lane = u & 63;
  const int wid = u >> 6;
  const int p = u >> 2, c = u & 3;
  // storage swizzle: slot(x) = x ^ ((x>>8)<<3)
  const int rdoff = (c << 8) | (p ^ (c << 3));   // slot(p + 256c)
  const int wroff = u ^ ((u & 0x300) >> 5);      // slot(u)

  ap[u] = 1.f; ap[SD + u] = 1.f;   // A0 = 1 (all-equal -> swizzle-invariant)
  float a_cur = 1.f;
  float nLf = 0.f;                 // -(L to apply THIS step)
  int Lnext = 0, cacc = 0;

  const float K = 1.44269504088896340736f;    // log2(e)
  const float LN2 = 0.69314718055994530942f;  // ln(2)

  const float* sn = scores + (size_t)n * CD + (size_t)u * 5;
  const size_t tstr = (size_t)NB * CD;
  const size_t str4 = 4 * tstr;

  auto CP = [&](int t, const f4a& qa, float qb) {
    const int rb = ((t + 1) & 1) * SD;
    const float vr = ap[rb + rdoff];    // pred read, conflict-free
    const float R = ap[rb];             // uniform addr -> broadcast
    // quad exchange on the VALU pipe
    const float p0 = dppq<0x00>(vr);    // A[p]
    const float p1 = dppq<0x55>(vr);    // A[256+p]
    const float p2 = dppq<0xAA>(vr);    // A[512+p]
    const float p3 = dppq<0xFF>(vr);    // A[768+p]
    // e's depend on prefetched scores + PREVIOUS step's broadcast -> fill
    // the ds_read latency shadow.
    float e0 = fexp2(__builtin_fmaf(qa.x, K, nLf));
    float e1 = fexp2(__builtin_fmaf(qa.y, K, nLf));
    float e2 = fexp2(__builtin_fmaf(qa.z, K, nLf));
    float e3 = fexp2(__builtin_fmaf(qa.w, K, nLf));
    float e4 = fexp2(__builtin_fmaf(qb,   K, nLf));
    float s = e0 * a_cur;
    s = __builtin_fmaf(e1, p0, s);
    s = __builtin_fmaf(e2, p1, s);
    s = __builtin_fmaf(e3, p2, s);
    s = __builtin_fmaf(e4, p3, s);
    a_cur = s;
    cacc += Lnext;                      // L applied in THIS step's e's
    ap[(t & 1) * SD + wroff] = s;       // ds_write_b32, 2-way = free
    // damped controller for next step: gain 1/4, lag 1
    const int xb = ((__float_as_int(R) >> 23) & 0xFF) - 127;
    Lnext = xb >> 2;                    // floor(x/4)
    nLf = (float)(-Lnext);
    // drain LDS only; global prefetches stay in flight across the barrier.
    asm volatile("s_waitcnt lgkmcnt(0)\n\ts_barrier" ::: "memory");
  };

  // 4 register sets + running pointers, clamped prologue.
#define PRO(cc)                                                             \
  const float* P##cc = sn + (size_t)((cc) < T ? (cc) : T - 1) * tstr;       \
  f4a qa##cc = *(const f4a*)P##cc;                                          \
  float qb##cc = P##cc[4];                                                  \
  P##cc += str4;
  PRO(0) PRO(1) PRO(2) PRO(3)
#undef PRO

  __syncthreads();  // ap init visible

#define RL(cc)                                                              \
  qa##cc = *(const f4a*)P##cc;                                              \
  qb##cc = P##cc[4];                                                        \
  P##cc += str4;

  int t = 0;
  for (; t + 8 <= T; t += 4) {
    CP(t + 0, qa0, qb0); RL(0)
    CP(t + 1, qa1, qb1); RL(1)
    CP(t + 2, qa2, qb2); RL(2)
    CP(t + 3, qa3, qb3); RL(3)
  }
#undef RL

#define EPI1(cc)                                                            \
  if (t + (cc) < T) {                                                       \
    CP(t + (cc), qa##cc, qb##cc);                                           \
    if (t + 4 + (cc) < T) { qa##cc = *(const f4a*)P##cc; qb##cc = P##cc[4]; }\
  }
  EPI1(0) EPI1(1) EPI1(2) EPI1(3)
#undef EPI1
  t += 4;
#define EPI2(cc) if (t + (cc) < T) CP(t + (cc), qa##cc, qb##cc);
  EPI2(0) EPI2(1) EPI2(2) EPI2(3)
#undef EPI2

  // logZ[n] = ln2 * (cacc + log2(sum_s A_T[s]))
  float v = a_cur;
#pragma unroll
  for (int d = 1; d < 64; d <<= 1) v += __shfl_xor(v, d, 64);
  if (lane == 0) red[wid] = v;
  __syncthreads();
  if (u == 0) {
    float ssum = red[0];
#pragma unroll
    for (int i = 1; i < 16; ++i) ssum += red[i];
    out[n] = LN2 * ((float)cacc + flog2(ssum));
  }
}

extern "C" void kernel_launch(void* const* d_in, const int* in_sizes, int n_in,
                              void* d_out, int out_size, void* d_ws, size_t ws_size,
                              hipStream_t stream) {
  const float* scores = (const float*)d_in[0];
  float* out = (float*)d_out;
  const long long tot = (long long)in_sizes[0];
  const int T = (int)(tot / ((long long)NB * CD));
  ctc_logz<<<dim3(NB), dim3(1024), 0, stream>>>(scores, out, T);
}